// Round 3
// baseline (260.523 us; speedup 1.0000x reference)
//
#include <hip/hip_runtime.h>
#include <math.h>

// PHM adapter: down (768->192, n=4 rank-1 kron) -> gelu_new -> up (192->768).
// Round 3: round-2 counters showed DS-pipe bound (~144 DS ops/token, VALU 20%,
// HBM 25%). Changes: (1) 16-lane reductions via DPP row_ror adds (VALU pipe,
// zero DS), (2) cross-group gather with 3 xor-shuffles per i instead of 16
// __shfl, (3) all per-lane-constant weights in registers (Ld/Lu/rules); only
// W_right_u stays in LDS. DS ops/token ~144 -> ~48.

#define SQ2PI 0.79788456080286535588f
#define T_TILE 8   // tokens per block-iteration; 8*768*4B = 24 KB tile

template<int CTRL>
__device__ __forceinline__ float ror_add(float v) {
    // v + rotate_within_16(v, CTRL)   (DPP row_ror — VALU pipe, no DS)
    int s = __builtin_amdgcn_update_dpp(0, __float_as_int(v), CTRL, 0xF, 0xF, true);
    return v + __int_as_float(s);
}
__device__ __forceinline__ float reduce16(float v) {
    v = ror_add<0x121>(v);   // row_ror:1
    v = ror_add<0x122>(v);   // row_ror:2
    v = ror_add<0x124>(v);   // row_ror:4
    v = ror_add<0x128>(v);   // row_ror:8
    return v;                // every lane: sum of its 16-lane row
}

__global__ __launch_bounds__(256, 3)
void phm_fused(const float* __restrict__ x,
               const float* __restrict__ rule_d,
               const float* __restrict__ Wl_d,
               const float* __restrict__ Wr_d,
               const float* __restrict__ bias_d,
               const float* __restrict__ rule_u,
               const float* __restrict__ Wl_u,
               const float* __restrict__ Wr_u,
               const float* __restrict__ bias_u,
               float* __restrict__ out,
               int n_tokens)
{
    __shared__ __attribute__((aligned(16))) float sTile[T_TILE * 768]; // 24 KB, in-place in/out
    __shared__ __attribute__((aligned(16))) float sRu[768];            // W_right_u [i][q2] i*192+q2

    const int tid = threadIdx.x;
    for (int i = tid; i < 768; i += 256) sRu[i] = Wr_u[i];

    const int lane = tid & 63;
    const int wave = tid >> 6;
    const int a    = lane >> 4;   // kron block 0..3 (also c for z-phase outputs)
    const int r    = lane & 15;   // slot within block

    // ---- per-lane-constant weights -> registers (live across all tokens) ----
    float4 ld[4][3];               // W_left_d[i][12r+4u .. +3]
    #pragma unroll
    for (int i = 0; i < 4; ++i)
        #pragma unroll
        for (int u = 0; u < 3; ++u)
            ld[i][u] = *(const float4*)(Wl_d + i*192 + 12*r + 4*u);

    float lu[4][3];                // W_left_u[i][3r+w]
    #pragma unroll
    for (int i = 0; i < 4; ++i)
        #pragma unroll
        for (int w = 0; w < 3; ++w) lu[i][w] = Wl_u[i*48 + 3*r + w];

    // rules pre-gathered for my destination c==a, source groups a^0..a^3
    float rD[4][4], rU[4][4];      // [xor_k][i] = rule[i][a^k][a]
    #pragma unroll
    for (int k = 0; k < 4; ++k)
        #pragma unroll
        for (int i = 0; i < 4; ++i) {
            rD[k][i] = rule_d[i*16 + (a^k)*4 + a];
            rU[k][i] = rule_u[i*16 + (a^k)*4 + a];
        }

    float bd[3];                   // bias_d at o = a*48 + 3r + w
    float rdw[4][3];               // W_right_d[i][3r+w]
    float4 bu[3];                  // bias_u at o = a*192 + 12r + 4u
    #pragma unroll
    for (int w = 0; w < 3; ++w) bd[w] = bias_d[a*48 + 3*r + w];
    #pragma unroll
    for (int i = 0; i < 4; ++i)
        #pragma unroll
        for (int w = 0; w < 3; ++w) rdw[i][w] = Wr_d[i*48 + 3*r + w];
    #pragma unroll
    for (int u = 0; u < 3; ++u)
        bu[u] = *(const float4*)(bias_u + a*192 + 12*r + 4*u);

    __syncthreads();

    const long long total4 = (long long)n_tokens * 192;   // total float4 count
    const int n_tiles = (n_tokens + T_TILE - 1) / T_TILE;

    for (int tile = blockIdx.x; tile < n_tiles; tile += gridDim.x) {
        const long long g4 = (long long)tile * (T_TILE * 192);

        // ---- cooperative coalesced stage: 1536 float4 / 256 threads ----
        #pragma unroll
        for (int j = 0; j < (T_TILE * 192) / 256; ++j) {
            const int idx = tid + j * 256;
            const long long gi = g4 + idx;
            float4 v = make_float4(0.f, 0.f, 0.f, 0.f);
            if (gi < total4) v = *(const float4*)(x + gi * 4);
            *(float4*)&sTile[idx * 4] = v;
        }
        __syncthreads();

        // ---- compute: each wave owns T_TILE/4 tokens, in-place in sTile ----
        #pragma unroll
        for (int s = 0; s < T_TILE / 4; ++s) {
            const int tloc = wave * (T_TILE / 4) + s;
            const int tok  = tile * T_TILE + tloc;
            if (tok < n_tokens) {
                float* xt = &sTile[tloc * 768 + a * 192 + 12 * r];
                float4 xv[3];
                #pragma unroll
                for (int u = 0; u < 3; ++u) xv[u] = *(const float4*)(xt + 4 * u);

                // down dots: partials over my 12 p's, then DPP 16-lane reduce
                float sd[4];
                #pragma unroll
                for (int i = 0; i < 4; ++i) {
                    float acc = 0.f;
                    #pragma unroll
                    for (int u = 0; u < 3; ++u) {
                        acc = fmaf(xv[u].x, ld[i][u].x, acc);
                        acc = fmaf(xv[u].y, ld[i][u].y, acc);
                        acc = fmaf(xv[u].z, ld[i][u].z, acc);
                        acc = fmaf(xv[u].w, ld[i][u].w, acc);
                    }
                    sd[i] = reduce16(acc);     // s[i][a] on every lane of group a
                }

                // cross-group gather: 3 shuffles per i (xor16, xor32, xor32(xor16))
                float tD[4];
                #pragma unroll
                for (int i = 0; i < 4; ++i) {
                    const float x1 = __shfl_xor(sd[i], 16);   // s[i][a^1]
                    const float x2 = __shfl_xor(sd[i], 32);   // s[i][a^2]
                    const float x3 = __shfl_xor(x1,    32);   // s[i][a^3]
                    tD[i] = fmaf(sd[i], rD[0][i],
                            fmaf(x1,   rD[1][i],
                            fmaf(x2,   rD[2][i],
                                 x3 *  rD[3][i])));
                }

                // z + gelu at o = a*48 + 3r + w
                float g[3];
                #pragma unroll
                for (int w = 0; w < 3; ++w) {
                    float z = bd[w];
                    #pragma unroll
                    for (int i = 0; i < 4; ++i) z = fmaf(tD[i], rdw[i][w], z);
                    const float inner = SQ2PI * fmaf(0.044715f*z, z*z, z);
                    const float e  = __expf(2.0f*inner);      // tanh(y)=1-2/(e^{2y}+1)
                    const float th = 1.0f - 2.0f/(e + 1.0f);
                    g[w] = 0.5f*z*(1.0f + th);
                }

                // up dots + DPP reduce + gather + rule contraction
                float tU[4];
                #pragma unroll
                for (int i = 0; i < 4; ++i) {
                    float acc = 0.f;
                    #pragma unroll
                    for (int w = 0; w < 3; ++w) acc = fmaf(g[w], lu[i][w], acc);
                    const float h  = reduce16(acc);           // h[i][a]
                    const float x1 = __shfl_xor(h,  16);
                    const float x2 = __shfl_xor(h,  32);
                    const float x3 = __shfl_xor(x1, 32);
                    tU[i] = fmaf(h,  rU[0][i],
                            fmaf(x1, rU[1][i],
                            fmaf(x2, rU[2][i],
                                 x3 * rU[3][i])));
                }

                // output chunk back IN PLACE (lane overwrites exactly what it read)
                #pragma unroll
                for (int u = 0; u < 3; ++u) {
                    float4 ov = bu[u];
                    #pragma unroll
                    for (int i = 0; i < 4; ++i) {
                        const float4 ru = *(const float4*)(&sRu[i*192 + 12*r + 4*u]);
                        ov.x = fmaf(tU[i], ru.x, ov.x);
                        ov.y = fmaf(tU[i], ru.y, ov.y);
                        ov.z = fmaf(tU[i], ru.z, ov.z);
                        ov.w = fmaf(tU[i], ru.w, ov.w);
                    }
                    *(float4*)(xt + 4 * u) = ov;
                }
            }
        }
        __syncthreads();

        // ---- cooperative coalesced store ----
        #pragma unroll
        for (int j = 0; j < (T_TILE * 192) / 256; ++j) {
            const int idx = tid + j * 256;
            const long long gi = g4 + idx;
            if (gi < total4)
                *(float4*)(out + gi * 4) = *(const float4*)&sTile[idx * 4];
        }
        __syncthreads();   // protect sTile before next tile's staging
    }
}

extern "C" void kernel_launch(void* const* d_in, const int* in_sizes, int n_in,
                              void* d_out, int out_size, void* d_ws, size_t ws_size,
                              hipStream_t stream) {
    const float* x      = (const float*)d_in[0];
    const float* rule_d = (const float*)d_in[1];
    const float* Wl_d   = (const float*)d_in[2];
    const float* Wr_d   = (const float*)d_in[3];
    const float* bias_d = (const float*)d_in[4];
    const float* rule_u = (const float*)d_in[5];
    const float* Wl_u   = (const float*)d_in[6];
    const float* Wr_u   = (const float*)d_in[7];
    const float* bias_u = (const float*)d_in[8];
    float* out          = (float*)d_out;

    const int n_tokens = in_sizes[0] / 768;   // 32768

    phm_fused<<<dim3(1024), dim3(256), 0, stream>>>(
        x, rule_d, Wl_d, Wr_d, bias_d, rule_u, Wl_u, Wr_u, bias_u, out, n_tokens);
}

// Round 4
// 207.101 us; speedup vs baseline: 1.2580x; 1.2580x over previous
//
#include <hip/hip_runtime.h>
#include <math.h>

// PHM adapter: down (768->192, n=4 rank-1 kron) -> gelu_new -> up (192->768).
// Round 4: round-3 regressed from register SPILL (48-reg ld[] array spilled to
// scratch: WRITE +12.6MB = 48B/thread, VALUBusy 11%). Fix: big weights back in
// LDS (round-2 style), keep DPP 16-lane reductions + 3-swizzle xor gather
// (round-3's real win), and amortize every LDS weight read over the wave's TWO
// tokens (computed in one pass). Persistent regs: only rD/rU/lu/rdw/bd (59).

#define SQ2PI 0.79788456080286535588f
#define T_TILE 8   // tokens per block-iteration; 24 KB tile; 4 waves x 2 tokens

template<int CTRL>
__device__ __forceinline__ float ror_add(float v) {
    // v + rotate_within_16(v, CTRL)  (DPP row_ror — VALU pipe, no DS traffic)
    int s = __builtin_amdgcn_update_dpp(0, __float_as_int(v), CTRL, 0xF, 0xF, true);
    return v + __int_as_float(s);
}
__device__ __forceinline__ float reduce16(float v) {
    v = ror_add<0x121>(v);   // row_ror:1
    v = ror_add<0x122>(v);   // row_ror:2
    v = ror_add<0x124>(v);   // row_ror:4
    v = ror_add<0x128>(v);   // row_ror:8
    return v;                // every lane: sum over its 16-lane row
}

__global__ __launch_bounds__(256, 4)
void phm_fused(const float* __restrict__ x,
               const float* __restrict__ rule_d,
               const float* __restrict__ Wl_d,
               const float* __restrict__ Wr_d,
               const float* __restrict__ bias_d,
               const float* __restrict__ rule_u,
               const float* __restrict__ Wl_u,
               const float* __restrict__ Wr_u,
               const float* __restrict__ bias_u,
               float* __restrict__ out,
               int n_tokens)
{
    __shared__ __attribute__((aligned(16))) float sTile[T_TILE * 768]; // 24 KB in/out, in-place
    __shared__ __attribute__((aligned(16))) float sLd[768];   // W_left_d  [i][p]  i*192+p
    __shared__ __attribute__((aligned(16))) float sRu[768];   // W_right_u [i][q2] i*192+q2
    __shared__ __attribute__((aligned(16))) float sBu[768];   // bias_u    [o]

    const int tid = threadIdx.x;
    for (int i = tid; i < 768; i += 256) sLd[i] = Wl_d[i];
    for (int i = tid; i < 768; i += 256) sRu[i] = Wr_u[i];
    for (int i = tid; i < 768; i += 256) sBu[i] = bias_u[i];

    const int lane = tid & 63;
    const int wave = tid >> 6;
    const int a    = lane >> 4;   // kron block 0..3 (also c for z-phase outputs)
    const int r    = lane & 15;   // slot within block

    // ---- SMALL per-lane-constant weights -> registers (59 floats total) ----
    float rD[4][4], rU[4][4];      // [xor_k][i] = rule[i][a^k][a]
    #pragma unroll
    for (int k = 0; k < 4; ++k)
        #pragma unroll
        for (int i = 0; i < 4; ++i) {
            rD[k][i] = rule_d[i*16 + (a^k)*4 + a];
            rU[k][i] = rule_u[i*16 + (a^k)*4 + a];
        }
    float lu[4][3];                // W_left_u[i][3r+w]
    #pragma unroll
    for (int i = 0; i < 4; ++i)
        #pragma unroll
        for (int w = 0; w < 3; ++w) lu[i][w] = Wl_u[i*48 + 3*r + w];
    float bd[3];                   // bias_d at o = a*48 + 3r + w
    float rdw[4][3];               // W_right_d[i][3r+w]
    #pragma unroll
    for (int w = 0; w < 3; ++w) bd[w] = bias_d[a*48 + 3*r + w];
    #pragma unroll
    for (int i = 0; i < 4; ++i)
        #pragma unroll
        for (int w = 0; w < 3; ++w) rdw[i][w] = Wr_d[i*48 + 3*r + w];

    __syncthreads();

    const long long total4 = (long long)n_tokens * 192;   // total float4 count
    const int n_tiles = (n_tokens + T_TILE - 1) / T_TILE;

    for (int tile = blockIdx.x; tile < n_tiles; tile += gridDim.x) {
        const long long g4 = (long long)tile * (T_TILE * 192);

        // ---- cooperative coalesced stage (zero-fill OOB) ----
        #pragma unroll
        for (int j = 0; j < (T_TILE * 192) / 256; ++j) {
            const int idx = tid + j * 256;
            const long long gi = g4 + idx;
            float4 v = make_float4(0.f, 0.f, 0.f, 0.f);
            if (gi < total4) v = *(const float4*)(x + gi * 4);
            *(float4*)&sTile[idx * 4] = v;
        }
        __syncthreads();

        // ---- compute: wave's TWO tokens in one pass (weight reads shared) ----
        float* xt0 = &sTile[(wave*2) * 768 + a*192 + 12*r];
        float* xt1 = xt0 + 768;
        float4 xv0[3], xv1[3];
        #pragma unroll
        for (int u = 0; u < 3; ++u) {
            xv0[u] = *(const float4*)(xt0 + 4*u);
            xv1[u] = *(const float4*)(xt1 + 4*u);
        }

        // down dots (one sLd read feeds both tokens), DPP 16-lane reduce
        float sd0[4], sd1[4];
        #pragma unroll
        for (int i = 0; i < 4; ++i) {
            float a0 = 0.f, a1 = 0.f;
            #pragma unroll
            for (int u = 0; u < 3; ++u) {
                const float4 lv = *(const float4*)(&sLd[i*192 + 12*r + 4*u]);
                a0 = fmaf(xv0[u].x, lv.x, a0);  a1 = fmaf(xv1[u].x, lv.x, a1);
                a0 = fmaf(xv0[u].y, lv.y, a0);  a1 = fmaf(xv1[u].y, lv.y, a1);
                a0 = fmaf(xv0[u].z, lv.z, a0);  a1 = fmaf(xv1[u].z, lv.z, a1);
                a0 = fmaf(xv0[u].w, lv.w, a0);  a1 = fmaf(xv1[u].w, lv.w, a1);
            }
            sd0[i] = reduce16(a0);
            sd1[i] = reduce16(a1);
        }

        // cross-group gather: 3 xor-shuffles per (i, token)
        float tD0[4], tD1[4];
        #pragma unroll
        for (int i = 0; i < 4; ++i) {
            float x1 = __shfl_xor(sd0[i], 16);
            float x2 = __shfl_xor(sd0[i], 32);
            float x3 = __shfl_xor(x1,     32);
            tD0[i] = fmaf(sd0[i], rD[0][i], fmaf(x1, rD[1][i],
                     fmaf(x2,     rD[2][i],      x3 * rD[3][i])));
            x1 = __shfl_xor(sd1[i], 16);
            x2 = __shfl_xor(sd1[i], 32);
            x3 = __shfl_xor(x1,     32);
            tD1[i] = fmaf(sd1[i], rD[0][i], fmaf(x1, rD[1][i],
                     fmaf(x2,     rD[2][i],      x3 * rD[3][i])));
        }

        // z + gelu at o = a*48 + 3r + w, both tokens
        float g0[3], g1[3];
        #pragma unroll
        for (int w = 0; w < 3; ++w) {
            float z0 = bd[w], z1 = bd[w];
            #pragma unroll
            for (int i = 0; i < 4; ++i) {
                z0 = fmaf(tD0[i], rdw[i][w], z0);
                z1 = fmaf(tD1[i], rdw[i][w], z1);
            }
            const float i0 = SQ2PI * fmaf(0.044715f*z0, z0*z0, z0);
            const float i1 = SQ2PI * fmaf(0.044715f*z1, z1*z1, z1);
            const float e0 = __expf(2.0f*i0);              // tanh(y)=1-2/(e^{2y}+1)
            const float e1 = __expf(2.0f*i1);
            g0[w] = 0.5f*z0*(1.0f + (1.0f - 2.0f/(e0 + 1.0f)));
            g1[w] = 0.5f*z1*(1.0f + (1.0f - 2.0f/(e1 + 1.0f)));
        }

        // up dots + DPP reduce + gather + rule contraction
        float tU0[4], tU1[4];
        #pragma unroll
        for (int i = 0; i < 4; ++i) {
            float a0 = 0.f, a1 = 0.f;
            #pragma unroll
            for (int w = 0; w < 3; ++w) {
                a0 = fmaf(g0[w], lu[i][w], a0);
                a1 = fmaf(g1[w], lu[i][w], a1);
            }
            const float h0 = reduce16(a0);
            const float h1 = reduce16(a1);
            float x1 = __shfl_xor(h0, 16);
            float x2 = __shfl_xor(h0, 32);
            float x3 = __shfl_xor(x1, 32);
            tU0[i] = fmaf(h0, rU[0][i], fmaf(x1, rU[1][i],
                     fmaf(x2, rU[2][i],      x3 * rU[3][i])));
            x1 = __shfl_xor(h1, 16);
            x2 = __shfl_xor(h1, 32);
            x3 = __shfl_xor(x1, 32);
            tU1[i] = fmaf(h1, rU[0][i], fmaf(x1, rU[1][i],
                     fmaf(x2, rU[2][i],      x3 * rU[3][i])));
        }

        // outputs back IN PLACE (lane overwrites exactly what it read; one
        // sRu/sBu read per u feeds both tokens)
        #pragma unroll
        for (int u = 0; u < 3; ++u) {
            const float4 b = *(const float4*)(&sBu[a*192 + 12*r + 4*u]);
            float4 ov0 = b, ov1 = b;
            #pragma unroll
            for (int i = 0; i < 4; ++i) {
                const float4 ru = *(const float4*)(&sRu[i*192 + 12*r + 4*u]);
                ov0.x = fmaf(tU0[i], ru.x, ov0.x);  ov1.x = fmaf(tU1[i], ru.x, ov1.x);
                ov0.y = fmaf(tU0[i], ru.y, ov0.y);  ov1.y = fmaf(tU1[i], ru.y, ov1.y);
                ov0.z = fmaf(tU0[i], ru.z, ov0.z);  ov1.z = fmaf(tU1[i], ru.z, ov1.z);
                ov0.w = fmaf(tU0[i], ru.w, ov0.w);  ov1.w = fmaf(tU1[i], ru.w, ov1.w);
            }
            *(float4*)(xt0 + 4*u) = ov0;
            *(float4*)(xt1 + 4*u) = ov1;
        }
        __syncthreads();

        // ---- cooperative coalesced store ----
        #pragma unroll
        for (int j = 0; j < (T_TILE * 192) / 256; ++j) {
            const int idx = tid + j * 256;
            const long long gi = g4 + idx;
            if (gi < total4)
                *(float4*)(out + gi * 4) = *(const float4*)&sTile[idx * 4];
        }
        __syncthreads();   // protect sTile before next tile's staging
    }
}

extern "C" void kernel_launch(void* const* d_in, const int* in_sizes, int n_in,
                              void* d_out, int out_size, void* d_ws, size_t ws_size,
                              hipStream_t stream) {
    const float* x      = (const float*)d_in[0];
    const float* rule_d = (const float*)d_in[1];
    const float* Wl_d   = (const float*)d_in[2];
    const float* Wr_d   = (const float*)d_in[3];
    const float* bias_d = (const float*)d_in[4];
    const float* rule_u = (const float*)d_in[5];
    const float* Wl_u   = (const float*)d_in[6];
    const float* Wr_u   = (const float*)d_in[7];
    const float* bias_u = (const float*)d_in[8];
    float* out          = (float*)d_out;

    const int n_tokens = in_sizes[0] / 768;   // 32768

    phm_fused<<<dim3(1024), dim3(256), 0, stream>>>(
        x, rule_d, Wl_d, Wr_d, bias_d, rule_u, Wl_u, Wr_u, bias_u, out, n_tokens);
}